// Round 1
// baseline (851.993 us; speedup 1.0000x reference)
//
#include <hip/hip_runtime.h>
#include <hip/hip_bf16.h>
#include <math.h>

#define BB 4
#define TT 4096
#define DD 512
#define HH 64
#define TW (TT/32)   // 128 bitmask words per dag row

typedef unsigned int u32;

// ---------------------------------------------------------------------------
// Pack dag (int32 0/1, [T,T]) into bitmask: bit=1 means "keep" (dag!=0).
// ---------------------------------------------------------------------------
__global__ __launch_bounds__(256) void pack_dag_kernel(const int* __restrict__ dag,
                                                       u32* __restrict__ bits) {
    int idx = blockIdx.x * 256 + threadIdx.x;
    int lane = threadIdx.x & 63;
    unsigned long long m = __ballot(dag[idx] != 0);
    if ((lane & 31) == 0) bits[idx >> 5] = (u32)(m >> (lane & 32));
}

// ---------------------------------------------------------------------------
// Fused QKV projection: [B*T, D] x [D, HS] -> Q,K,V [B*T, HS]. fp32.
// Block: 256 threads, tile 64 rows x 64 cols, K-chunks of 64.
// ---------------------------------------------------------------------------
__global__ __launch_bounds__(256) void proj_kernel(const float* __restrict__ X,
                                                   const float* __restrict__ Wq,
                                                   const float* __restrict__ Wk,
                                                   const float* __restrict__ Wv,
                                                   float* __restrict__ Qo,
                                                   float* __restrict__ Ko,
                                                   float* __restrict__ Vo) {
    __shared__ float Xs[64][65];
    __shared__ float Ws[3][64][65];
    const int r0 = blockIdx.x * 64;
    const int tid = threadIdx.x;
    const int tx = tid & 15, ty = tid >> 4;
    const int col = tid & 63, rb = tid >> 6;

    float accQ[4][4] = {}, accK[4][4] = {}, accV[4][4] = {};

    for (int d0 = 0; d0 < DD; d0 += 64) {
#pragma unroll
        for (int k = 0; k < 16; ++k) {
            int row = rb + k * 4;
            Xs[row][col]    = X[(size_t)(r0 + row) * DD + d0 + col];
            Ws[0][row][col] = Wq[(size_t)(d0 + row) * HH + col];
            Ws[1][row][col] = Wk[(size_t)(d0 + row) * HH + col];
            Ws[2][row][col] = Wv[(size_t)(d0 + row) * HH + col];
        }
        __syncthreads();
#pragma unroll 8
        for (int kk = 0; kk < 64; ++kk) {
            float xf[4], wq[4], wk[4], wv[4];
#pragma unroll
            for (int r = 0; r < 4; ++r) xf[r] = Xs[ty * 4 + r][kk];
#pragma unroll
            for (int c = 0; c < 4; ++c) {
                wq[c] = Ws[0][kk][tx * 4 + c];
                wk[c] = Ws[1][kk][tx * 4 + c];
                wv[c] = Ws[2][kk][tx * 4 + c];
            }
#pragma unroll
            for (int r = 0; r < 4; ++r)
#pragma unroll
                for (int c = 0; c < 4; ++c) {
                    accQ[r][c] += xf[r] * wq[c];
                    accK[r][c] += xf[r] * wk[c];
                    accV[r][c] += xf[r] * wv[c];
                }
        }
        __syncthreads();
    }
#pragma unroll
    for (int r = 0; r < 4; ++r) {
        size_t o = (size_t)(r0 + ty * 4 + r) * HH + tx * 4;
        float4 q4 = make_float4(accQ[r][0], accQ[r][1], accQ[r][2], accQ[r][3]);
        float4 k4 = make_float4(accK[r][0], accK[r][1], accK[r][2], accK[r][3]);
        float4 v4 = make_float4(accV[r][0], accV[r][1], accV[r][2], accV[r][3]);
        *(float4*)&Qo[o] = q4;
        *(float4*)&Ko[o] = k4;
        *(float4*)&Vo[o] = v4;
    }
}

// ---------------------------------------------------------------------------
// Stats pass: per (b,i) compute m_i = max_j S, l_i = sum_j exp(S-m), with
// dag mask. S[i,j] = Q[i]·K[j] / 8. Block handles 64 i-rows.
// ---------------------------------------------------------------------------
__global__ __launch_bounds__(256) void stats_kernel(const float* __restrict__ Q,
                                                    const float* __restrict__ K,
                                                    const u32* __restrict__ bits,
                                                    float* __restrict__ mOut,
                                                    float* __restrict__ lOut) {
    __shared__ float Qs[64][65];
    __shared__ float Ks[64][65];
    __shared__ float Ms[64][17];
    __shared__ float Ls[64][17];

    const int b  = blockIdx.x >> 6;
    const int i0 = (blockIdx.x & 63) * 64;
    const int tid = threadIdx.x;
    const int tx = tid & 15, ty = tid >> 4;
    const int col = tid & 63, rb = tid >> 6;

#pragma unroll
    for (int k = 0; k < 16; ++k) {
        int row = rb + k * 4;
        Qs[row][col] = Q[((size_t)b * TT + i0 + row) * HH + col];
    }

    float m[4], l[4];
#pragma unroll
    for (int r = 0; r < 4; ++r) { m[r] = -INFINITY; l[r] = 0.f; }

    for (int j0 = 0; j0 < TT; j0 += 64) {
#pragma unroll
        for (int k = 0; k < 16; ++k) {
            int row = rb + k * 4;
            Ks[row][col] = K[((size_t)b * TT + j0 + row) * HH + col];
        }
        __syncthreads();

        float s[4][4] = {};
#pragma unroll 8
        for (int kk = 0; kk < 64; ++kk) {
            float qf[4], kf[4];
#pragma unroll
            for (int r = 0; r < 4; ++r) qf[r] = Qs[ty * 4 + r][kk];
#pragma unroll
            for (int c = 0; c < 4; ++c) kf[c] = Ks[tx * 4 + c][kk];
#pragma unroll
            for (int r = 0; r < 4; ++r)
#pragma unroll
                for (int c = 0; c < 4; ++c) s[r][c] += qf[r] * kf[c];
        }

#pragma unroll
        for (int r = 0; r < 4; ++r) {
            int i = i0 + ty * 4 + r;
            u32 w = bits[(size_t)i * TW + ((j0 + tx * 4) >> 5)];
            float sv[4];
            float tmax = -INFINITY;
#pragma unroll
            for (int c = 0; c < 4; ++c) {
                int j = j0 + tx * 4 + c;
                bool keep = (w >> (j & 31)) & 1u;
                float x = s[r][c] * 0.125f;
                sv[c] = keep ? x : -INFINITY;
                tmax = fmaxf(tmax, sv[c]);
            }
            if (tmax > m[r]) { l[r] *= expf(m[r] - tmax); m[r] = tmax; }
            if (m[r] > -INFINITY) {
#pragma unroll
                for (int c = 0; c < 4; ++c)
                    if (sv[c] > -INFINITY) l[r] += expf(sv[c] - m[r]);
            }
        }
        __syncthreads();
    }

    // merge 16 tx-partials per row
#pragma unroll
    for (int r = 0; r < 4; ++r) { Ms[ty * 4 + r][tx] = m[r]; Ls[ty * 4 + r][tx] = l[r]; }
    __syncthreads();
    if (tid < 64) {
        float mm = -INFINITY;
#pragma unroll
        for (int k = 0; k < 16; ++k) mm = fmaxf(mm, Ms[tid][k]);
        float ll = 0.f;
        if (mm > -INFINITY) {
#pragma unroll
            for (int k = 0; k < 16; ++k) ll += Ls[tid][k] * expf(Ms[tid][k] - mm);
        }
        mOut[(size_t)b * TT + i0 + tid] = mm;
        lOut[(size_t)b * TT + i0 + tid] = ll;
    }
}

// ---------------------------------------------------------------------------
// Output pass: out[b,j,h] = sum_i P[i,j] * V[i,h], P = exp(S-m_i)/l_i masked.
// Block owns 64 j-rows of out (all 64 h). Loops over i-tiles of 64.
// Swish fused in epilogue.
// ---------------------------------------------------------------------------
__global__ __launch_bounds__(256) void out_kernel(const float* __restrict__ Q,
                                                  const float* __restrict__ K,
                                                  const float* __restrict__ V,
                                                  const u32* __restrict__ bits,
                                                  const float* __restrict__ mIn,
                                                  const float* __restrict__ lIn,
                                                  float* __restrict__ out) {
    __shared__ float Ks[64][65];
    __shared__ float Qs[64][65];
    __shared__ float Vs[64][65];
    __shared__ float Ps[64][65];
    __shared__ float mS[64];
    __shared__ float ilS[64];

    const int b  = blockIdx.x >> 6;
    const int j0 = (blockIdx.x & 63) * 64;
    const int tid = threadIdx.x;
    const int tx = tid & 15, ty = tid >> 4;
    const int col = tid & 63, rb = tid >> 6;

#pragma unroll
    for (int k = 0; k < 16; ++k) {
        int row = rb + k * 4;
        Ks[row][col] = K[((size_t)b * TT + j0 + row) * HH + col];
    }

    float acc[4][4] = {};

    for (int i0 = 0; i0 < TT; i0 += 64) {
#pragma unroll
        for (int k = 0; k < 16; ++k) {
            int row = rb + k * 4;
            Qs[row][col] = Q[((size_t)b * TT + i0 + row) * HH + col];
            Vs[row][col] = V[((size_t)b * TT + i0 + row) * HH + col];
        }
        if (tid < 64) {
            float mm = mIn[(size_t)b * TT + i0 + tid];
            float ll = lIn[(size_t)b * TT + i0 + tid];
            mS[tid]  = mm;
            ilS[tid] = (ll > 0.f) ? 1.f / ll : 0.f;
        }
        __syncthreads();

        // S tile: rows i (ty*4+r), cols j (tx*4+c)
        float s[4][4] = {};
#pragma unroll 8
        for (int kk = 0; kk < 64; ++kk) {
            float qf[4], kf[4];
#pragma unroll
            for (int r = 0; r < 4; ++r) qf[r] = Qs[ty * 4 + r][kk];
#pragma unroll
            for (int c = 0; c < 4; ++c) kf[c] = Ks[tx * 4 + c][kk];
#pragma unroll
            for (int r = 0; r < 4; ++r)
#pragma unroll
                for (int c = 0; c < 4; ++c) s[r][c] += qf[r] * kf[c];
        }

#pragma unroll
        for (int r = 0; r < 4; ++r) {
            int ii = ty * 4 + r;
            int i  = i0 + ii;
            u32 w = bits[(size_t)i * TW + ((j0 + tx * 4) >> 5)];
            float mi = mS[ii];
            float il = ilS[ii];
#pragma unroll
            for (int c = 0; c < 4; ++c) {
                int j = j0 + tx * 4 + c;
                bool keep = (w >> (j & 31)) & 1u;
                float p = keep ? expf(s[r][c] * 0.125f - mi) * il : 0.f;
                Ps[ii][tx * 4 + c] = p;
            }
        }
        __syncthreads();

        // out[j,h] += sum_ii P[ii][j] * V[ii][h]; thread: j = ty*4+r, h = tx*4+c
#pragma unroll 8
        for (int ii = 0; ii < 64; ++ii) {
            float pv[4], vv[4];
#pragma unroll
            for (int r = 0; r < 4; ++r) pv[r] = Ps[ii][ty * 4 + r];
#pragma unroll
            for (int c = 0; c < 4; ++c) vv[c] = Vs[ii][tx * 4 + c];
#pragma unroll
            for (int r = 0; r < 4; ++r)
#pragma unroll
                for (int c = 0; c < 4; ++c) acc[r][c] += pv[r] * vv[c];
        }
        __syncthreads();
    }

    // epilogue: swish, vectorized store
#pragma unroll
    for (int r = 0; r < 4; ++r) {
        float o4[4];
#pragma unroll
        for (int c = 0; c < 4; ++c) {
            float o = acc[r][c];
            o4[c] = o / (1.f + expf(-o));
        }
        size_t off = ((size_t)b * TT + j0 + ty * 4 + r) * HH + tx * 4;
        *(float4*)&out[off] = make_float4(o4[0], o4[1], o4[2], o4[3]);
    }
}

// ---------------------------------------------------------------------------
extern "C" void kernel_launch(void* const* d_in, const int* in_sizes, int n_in,
                              void* d_out, int out_size, void* d_ws, size_t ws_size,
                              hipStream_t stream) {
    const float* X  = (const float*)d_in[0];
    const int*  dag = (const int*)d_in[1];
    const float* Wk = (const float*)d_in[2];
    const float* Wq = (const float*)d_in[3];
    const float* Wv = (const float*)d_in[4];
    float* out = (float*)d_out;

    float* ws = (float*)d_ws;
    float* Q    = ws;
    float* K    = Q + (size_t)BB * TT * HH;
    float* V    = K + (size_t)BB * TT * HH;
    float* mBuf = V + (size_t)BB * TT * HH;
    float* lBuf = mBuf + (size_t)BB * TT;
    u32*   bits = (u32*)(lBuf + (size_t)BB * TT);
    // total ws usage ~14.2 MiB

    pack_dag_kernel<<<TT * TT / 256, 256, 0, stream>>>(dag, bits);
    proj_kernel<<<BB * TT / 64, 256, 0, stream>>>(X, Wq, Wk, Wv, Q, K, V);
    stats_kernel<<<BB * (TT / 64), 256, 0, stream>>>(Q, K, bits, mBuf, lBuf);
    out_kernel<<<BB * (TT / 64), 256, 0, stream>>>(Q, K, V, bits, mBuf, lBuf, out);
}

// Round 2
// 194.947 us; speedup vs baseline: 4.3704x; 4.3704x over previous
//
#include <hip/hip_runtime.h>
#include <hip/hip_bf16.h>
#include <math.h>

#define BB 4
#define TT 4096
#define DD 512
#define HH 64
#define TW 128   // TT/32 bitmask words per row

typedef unsigned int u32;
typedef unsigned short u16;
typedef float f32x16 __attribute__((ext_vector_type(16)));
typedef __bf16 bf16x8 __attribute__((ext_vector_type(8)));

static __device__ __forceinline__ u16 f2b(float f) {
    __hip_bfloat16 h = __float2bfloat16(f);
    return __builtin_bit_cast(u16, h);
}
static __device__ __forceinline__ u32 pk2(float a, float b) {
    return (u32)f2b(a) | ((u32)f2b(b) << 16);
}
static __device__ __forceinline__ bf16x8 ldf(const u16* p) {
    uint4 u = *(const uint4*)p;
    return __builtin_bit_cast(bf16x8, u);
}

// ---------------------------------------------------------------------------
// Pack dag into row-major bits[i][j/32] AND col-major bitsT[j][i/32].
// One wave handles 64 i-rows x 32 j-cols; per-lane 128B coalesced row read.
// ---------------------------------------------------------------------------
__global__ __launch_bounds__(256) void pack_kernel(const int* __restrict__ dag,
                                                   u32* __restrict__ bits,
                                                   u32* __restrict__ bitsT) {
    const int unit = blockIdx.x * 4 + (threadIdx.x >> 6);
    const int lane = threadIdx.x & 63;
    const int i64 = unit >> 7;    // 64 i-tiles (of 64 rows)
    const int j32 = unit & 127;   // 128 j-tiles (of 32 cols)
    const int i = i64 * 64 + lane;
    const int* p = dag + (size_t)i * TT + j32 * 32;
    u32 rw = 0;
#pragma unroll
    for (int c = 0; c < 32; c += 4) {
        int4 v = *(const int4*)(p + c);
        rw |= (v.x != 0 ? 1u : 0u) << c;
        rw |= (v.y != 0 ? 1u : 0u) << (c + 1);
        rw |= (v.z != 0 ? 1u : 0u) << (c + 2);
        rw |= (v.w != 0 ? 1u : 0u) << (c + 3);
    }
    bits[(size_t)i * TW + j32] = rw;
    u32 myw = 0;
#pragma unroll
    for (int c = 0; c < 32; ++c) {
        unsigned long long m = __ballot((rw >> c) & 1);
        u32 part = (lane < 32) ? (u32)m : (u32)(m >> 32);
        if ((lane & 31) == c) myw = part;
    }
    bitsT[(size_t)(j32 * 32 + (lane & 31)) * TW + i64 * 2 + (lane >> 5)] = myw;
}

// ---------------------------------------------------------------------------
// Projection (fp32 for accuracy): one of Q/K/V per blockIdx.y.
// Q,K written as bf16; V as f32 (scaled+transposed later).
// ---------------------------------------------------------------------------
__global__ __launch_bounds__(256) void proj_kernel(const float* __restrict__ X,
                                                   const float* __restrict__ Wq,
                                                   const float* __restrict__ Wk,
                                                   const float* __restrict__ Wv,
                                                   u16* __restrict__ Qb,
                                                   u16* __restrict__ Kb,
                                                   float* __restrict__ Vf) {
    __shared__ float Xs[64][65];
    __shared__ float Ws[64][65];
    const int which = blockIdx.y;
    const float* W = (which == 0) ? Wq : (which == 1) ? Wk : Wv;
    const int r0 = blockIdx.x * 64;
    const int tid = threadIdx.x;
    const int tx = tid & 15, ty = tid >> 4;
    const int col = tid & 63, rb = tid >> 6;

    float acc[4][4] = {};
    for (int d0 = 0; d0 < DD; d0 += 64) {
#pragma unroll
        for (int k = 0; k < 16; ++k) {
            int row = rb + k * 4;
            Xs[row][col] = X[(size_t)(r0 + row) * DD + d0 + col];
            Ws[row][col] = W[(size_t)(d0 + row) * HH + col];
        }
        __syncthreads();
#pragma unroll 8
        for (int kk = 0; kk < 64; ++kk) {
            float xf[4], wf[4];
#pragma unroll
            for (int r = 0; r < 4; ++r) xf[r] = Xs[ty * 4 + r][kk];
#pragma unroll
            for (int c = 0; c < 4; ++c) wf[c] = Ws[kk][tx * 4 + c];
#pragma unroll
            for (int r = 0; r < 4; ++r)
#pragma unroll
                for (int c = 0; c < 4; ++c) acc[r][c] += xf[r] * wf[c];
        }
        __syncthreads();
    }
    if (which < 2) {
        u16* dst = (which == 0) ? Qb : Kb;
#pragma unroll
        for (int r = 0; r < 4; ++r) {
            size_t o = (size_t)(r0 + ty * 4 + r) * HH + tx * 4;
            uint2 pw;
            pw.x = pk2(acc[r][0], acc[r][1]);
            pw.y = pk2(acc[r][2], acc[r][3]);
            *(uint2*)&dst[o] = pw;
        }
    } else {
#pragma unroll
        for (int r = 0; r < 4; ++r) {
            size_t o = (size_t)(r0 + ty * 4 + r) * HH + tx * 4;
            *(float4*)&Vf[o] = make_float4(acc[r][0], acc[r][1], acc[r][2], acc[r][3]);
        }
    }
}

// ---------------------------------------------------------------------------
// Stats: c[b,i] = 1 / sum_j mask(i,j)*exp(S_ij)   (0 if row dead).
// MFMA computes S^T tiles: A=K (m=j), B=Q (n=i). Lane: i = lane&31 fixed.
// Block = (b, 32 i-rows); 4 waves split j-tiles; LDS reduce.
// ---------------------------------------------------------------------------
__global__ __launch_bounds__(256) void stats_kernel(const u16* __restrict__ Qb,
                                                    const u16* __restrict__ Kb,
                                                    const u32* __restrict__ bits,
                                                    float* __restrict__ cOut) {
    __shared__ float Lsh[4][64];
    const int blk = blockIdx.x;
    const int b = blk >> 7, it = blk & 127;
    const int i0 = it * 32;
    const int w = threadIdx.x >> 6, lane = threadIdx.x & 63;
    const int l31 = lane & 31, hf = lane >> 5;

    bf16x8 qf[4];
    const u16* qbase = Qb + ((size_t)b * TT + i0 + l31) * HH + hf * 8;
#pragma unroll
    for (int kt = 0; kt < 4; ++kt) qf[kt] = ldf(qbase + kt * 16);

    const u32* brow = bits + (size_t)(i0 + l31) * TW;
    float Lp = 0.f;
    for (int jt = w; jt < 128; jt += 4) {
        const u16* kbase = Kb + ((size_t)b * TT + jt * 32 + l31) * HH + hf * 8;
        bf16x8 a0 = ldf(kbase), a1 = ldf(kbase + 16), a2 = ldf(kbase + 32), a3 = ldf(kbase + 48);
        u32 mw = brow[jt];
        f32x16 s = {};
        s = __builtin_amdgcn_mfma_f32_32x32x16_bf16(a0, qf[0], s, 0, 0, 0);
        s = __builtin_amdgcn_mfma_f32_32x32x16_bf16(a1, qf[1], s, 0, 0, 0);
        s = __builtin_amdgcn_mfma_f32_32x32x16_bf16(a2, qf[2], s, 0, 0, 0);
        s = __builtin_amdgcn_mfma_f32_32x32x16_bf16(a3, qf[3], s, 0, 0, 0);
#pragma unroll
        for (int r = 0; r < 16; ++r) {
            int jl = (r & 3) + 8 * (r >> 2) + 4 * hf;   // j-local (m dim)
            float e = __expf(s[r] * 0.125f);
            Lp += ((mw >> jl) & 1) ? e : 0.f;
        }
    }
    Lsh[w][lane] = Lp;
    __syncthreads();
    if (threadIdx.x < 32) {
        float L = 0.f;
#pragma unroll
        for (int q = 0; q < 4; ++q) L += Lsh[q][threadIdx.x] + Lsh[q][threadIdx.x + 32];
        cOut[(size_t)b * TT + i0 + threadIdx.x] = (L > 0.f) ? 1.f / L : 0.f;
    }
}

// ---------------------------------------------------------------------------
// Scale V rows by c_i, write transposed bf16 Vt[b][h][i].
// ---------------------------------------------------------------------------
__global__ __launch_bounds__(256) void scalev_kernel(const float* __restrict__ Vf,
                                                     const float* __restrict__ cB,
                                                     u16* __restrict__ Vt) {
    __shared__ u16 Lt[64][72];
    const int blk = blockIdx.x;
    const int b = blk >> 6, it = blk & 63;
    const int i0 = it * 64;
    const int t = threadIdx.x;
    const int row = t >> 2, seg = t & 3;
    const float cv = cB[(size_t)b * TT + i0 + row];
    const float* src = Vf + ((size_t)b * TT + i0 + row) * HH + seg * 16;
#pragma unroll
    for (int k = 0; k < 16; k += 4) {
        float4 v = *(const float4*)(src + k);
        Lt[seg * 16 + k + 0][row] = f2b(v.x * cv);
        Lt[seg * 16 + k + 1][row] = f2b(v.y * cv);
        Lt[seg * 16 + k + 2][row] = f2b(v.z * cv);
        Lt[seg * 16 + k + 3][row] = f2b(v.w * cv);
    }
    __syncthreads();
    const int h = row, cs = seg * 16;
    uint4 q0 = *(const uint4*)&Lt[h][cs];
    uint4 q1 = *(const uint4*)&Lt[h][cs + 8];
    u16* dst = Vt + ((size_t)b * HH + h) * TT + i0 + cs;
    *(uint4*)dst = q0;
    *(uint4*)(dst + 8) = q1;
}

// ---------------------------------------------------------------------------
// Output: out[b,j,h] = swish( sum_i mask*exp(S_ij) * Vt'[h][i] ).
// Block = (b, 32 j-cols); 4 waves split i-tiles; S via MFMA (lane: j=lane&31),
// P transposed to A-fragments via cvt_pk + shfl_xor(32); PV via MFMA.
// ---------------------------------------------------------------------------
__global__ __launch_bounds__(256) void out_kernel(const u16* __restrict__ Qb,
                                                  const u16* __restrict__ Kb,
                                                  const u16* __restrict__ Vt,
                                                  const u32* __restrict__ bitsT,
                                                  float* __restrict__ out) {
    __shared__ float red[4][2048];
    const int blk = blockIdx.x;
    const int b = blk >> 7, jt = blk & 127;
    const int j0 = jt * 32;
    const int w = threadIdx.x >> 6, lane = threadIdx.x & 63;
    const int l31 = lane & 31, hf = lane >> 5;

    bf16x8 kf[4];
    {
        const u16* kbase = Kb + ((size_t)b * TT + j0 + l31) * HH + hf * 8;
#pragma unroll
        for (int kt = 0; kt < 4; ++kt) kf[kt] = ldf(kbase + kt * 16);
    }
    const u16* qb0 = Qb + (size_t)b * TT * HH + hf * 8;
    const u16* vb0 = Vt + (size_t)b * HH * TT + (size_t)l31 * TT + hf * 8;
    const u32* btc = bitsT + (size_t)(j0 + l31) * TW;

    f32x16 acc0 = {}, acc1 = {};

    int it = w;
    {
    }
    const u16* qr = qb0 + (size_t)(it * 32 + l31) * HH;
    bf16x8 qf0 = ldf(qr), qf1 = ldf(qr + 16), qf2 = ldf(qr + 32), qf3 = ldf(qr + 48);
    u32 mw = btc[it];

    for (int t = 0; t < 32; ++t) {
        const int itn = (it + 4) & 127;
        const u16* vb = vb0 + it * 32;
        bf16x8 vf00 = ldf(vb);
        bf16x8 vf01 = ldf(vb + 16);
        bf16x8 vf10 = ldf(vb + (size_t)32 * TT);
        bf16x8 vf11 = ldf(vb + (size_t)32 * TT + 16);

        f32x16 s = {};
        s = __builtin_amdgcn_mfma_f32_32x32x16_bf16(qf0, kf[0], s, 0, 0, 0);
        s = __builtin_amdgcn_mfma_f32_32x32x16_bf16(qf1, kf[1], s, 0, 0, 0);
        s = __builtin_amdgcn_mfma_f32_32x32x16_bf16(qf2, kf[2], s, 0, 0, 0);
        s = __builtin_amdgcn_mfma_f32_32x32x16_bf16(qf3, kf[3], s, 0, 0, 0);

        // prefetch next tile's Q-frags + mask (wrap on last iter; unused)
        const u16* qr2 = qb0 + (size_t)(itn * 32 + l31) * HH;
        bf16x8 qn0 = ldf(qr2), qn1 = ldf(qr2 + 16), qn2 = ldf(qr2 + 32), qn3 = ldf(qr2 + 48);
        u32 mwn = btc[itn];

        float p[16];
#pragma unroll
        for (int r = 0; r < 16; ++r) {
            int il = (r & 3) + 8 * (r >> 2) + 4 * hf;   // i-local (m dim)
            float e = __expf(s[r] * 0.125f);
            p[r] = ((mw >> il) & 1) ? e : 0.f;
        }

#pragma unroll
        for (int k2 = 0; k2 < 2; ++k2) {
            u32 pA0 = pk2(p[8 * k2 + 0], p[8 * k2 + 1]);
            u32 pA1 = pk2(p[8 * k2 + 2], p[8 * k2 + 3]);
            u32 pB0 = pk2(p[8 * k2 + 4], p[8 * k2 + 5]);
            u32 pB1 = pk2(p[8 * k2 + 6], p[8 * k2 + 7]);
            u32 xA0 = (u32)__shfl_xor((int)pA0, 32, 64);
            u32 xA1 = (u32)__shfl_xor((int)pA1, 32, 64);
            u32 xB0 = (u32)__shfl_xor((int)pB0, 32, 64);
            u32 xB1 = (u32)__shfl_xor((int)pB1, 32, 64);
            uint4 aw;
            aw.x = hf ? xB0 : pA0;
            aw.y = hf ? xB1 : pA1;
            aw.z = hf ? pB0 : xA0;
            aw.w = hf ? pB1 : xA1;
            bf16x8 pa = __builtin_bit_cast(bf16x8, aw);
            if (k2 == 0) {
                acc0 = __builtin_amdgcn_mfma_f32_32x32x16_bf16(pa, vf00, acc0, 0, 0, 0);
                acc1 = __builtin_amdgcn_mfma_f32_32x32x16_bf16(pa, vf10, acc1, 0, 0, 0);
            } else {
                acc0 = __builtin_amdgcn_mfma_f32_32x32x16_bf16(pa, vf01, acc0, 0, 0, 0);
                acc1 = __builtin_amdgcn_mfma_f32_32x32x16_bf16(pa, vf11, acc1, 0, 0, 0);
            }
        }
        qf0 = qn0; qf1 = qn1; qf2 = qn2; qf3 = qn3; mw = mwn; it = itn;
    }

    float* myred = red[w];
#pragma unroll
    for (int r = 0; r < 16; ++r) {
        int jl = (r & 3) + 8 * (r >> 2) + 4 * hf;   // j-local (m dim)
        myred[jl * 64 + l31] = acc0[r];
        myred[jl * 64 + 32 + l31] = acc1[r];
    }
    __syncthreads();
    const int tid = threadIdx.x;
    const int base = tid * 8;
    float vals[8];
#pragma unroll
    for (int q = 0; q < 8; ++q) {
        int idx = base + q;
        float v = red[0][idx] + red[1][idx] + red[2][idx] + red[3][idx];
        vals[q] = v / (1.f + __expf(-v));
    }
    const int jl = base >> 6, hc = base & 63;
    float* dst = out + ((size_t)b * TT + j0 + jl) * HH + hc;
    *(float4*)dst = make_float4(vals[0], vals[1], vals[2], vals[3]);
    *(float4*)(dst + 4) = make_float4(vals[4], vals[5], vals[6], vals[7]);
}

// ---------------------------------------------------------------------------
extern "C" void kernel_launch(void* const* d_in, const int* in_sizes, int n_in,
                              void* d_out, int out_size, void* d_ws, size_t ws_size,
                              hipStream_t stream) {
    const float* X  = (const float*)d_in[0];
    const int*  dag = (const int*)d_in[1];
    const float* Wk = (const float*)d_in[2];
    const float* Wq = (const float*)d_in[3];
    const float* Wv = (const float*)d_in[4];
    float* out = (float*)d_out;

    char* ws = (char*)d_ws;
    u16*   Qb    = (u16*)ws;                               // 2 MB
    u16*   Kb    = (u16*)(ws + (2u << 20));                // 2 MB
    float* Vf    = (float*)(ws + (4u << 20));              // 4 MB
    u16*   Vt    = (u16*)(ws + (8u << 20));                // 2 MB
    float* cB    = (float*)(ws + (10u << 20));             // 64 KB
    u32*   bits  = (u32*)(ws + (10u << 20) + (1u << 16));  // 2 MB
    u32*   bitsT = (u32*)(ws + (12u << 20) + (1u << 16));  // 2 MB

    pack_kernel<<<2048, 256, 0, stream>>>(dag, bits, bitsT);
    proj_kernel<<<dim3(256, 3), 256, 0, stream>>>(X, Wq, Wk, Wv, Qb, Kb, Vf);
    stats_kernel<<<BB * 128, 256, 0, stream>>>(Qb, Kb, bits, cB);
    scalev_kernel<<<BB * 64, 256, 0, stream>>>(Vf, cB, Vt);
    out_kernel<<<BB * 128, 256, 0, stream>>>(Qb, Kb, Vt, bitsT, out);
}

// Round 3
// 162.979 us; speedup vs baseline: 5.2276x; 1.1962x over previous
//
#include <hip/hip_runtime.h>
#include <hip/hip_bf16.h>
#include <math.h>

#define BB 4
#define TT 4096
#define DD 512
#define HH 64
#define TW 128   // TT/32 bitmask words per row

typedef unsigned int u32;
typedef unsigned short u16;
typedef float f32x16 __attribute__((ext_vector_type(16)));
typedef __bf16 bf16x8 __attribute__((ext_vector_type(8)));

#define SC 0.18033688011112042f  /* 0.125 * log2(e) */

static __device__ __forceinline__ u16 f2b(float f) {
    __hip_bfloat16 h = __float2bfloat16(f);
    return __builtin_bit_cast(u16, h);
}
static __device__ __forceinline__ u32 pk2(float a, float b) {
    return (u32)f2b(a) | ((u32)f2b(b) << 16);
}
static __device__ __forceinline__ bf16x8 ldf(const u16* p) {
    uint4 u = *(const uint4*)p;
    return __builtin_bit_cast(bf16x8, u);
}
// swap high 32 lanes of a with low 32 lanes of b (both results used)
static __device__ __forceinline__ void swap32(u32& a, u32& b) {
    asm("v_permlane32_swap_b32 %0, %1" : "+v"(a), "+v"(b));
}

// ---------------------------------------------------------------------------
// Pack dag into row-major bits[i][j/32] AND col-major bitsT[j][i/32].
// Tail blocks (>=2048): transpose W{q,k,v} fp32 [512][64] -> bf16 Wt[3][64][512].
// ---------------------------------------------------------------------------
__global__ __launch_bounds__(256) void pack_kernel(const int* __restrict__ dag,
                                                   u32* __restrict__ bits,
                                                   u32* __restrict__ bitsT,
                                                   const float* __restrict__ Wq,
                                                   const float* __restrict__ Wk,
                                                   const float* __restrict__ Wv,
                                                   u16* __restrict__ Wt) {
    if (blockIdx.x >= 2048) {
        const int wb = blockIdx.x - 2048;     // 0..23
        const int m = wb >> 3, sub = wb & 7;
        const float* W = (m == 0) ? Wq : (m == 1) ? Wk : Wv;
        const int t = threadIdx.x;
        const int n = sub * 8 + (t >> 5);
        const int k0 = (t & 31) * 16;
        u16 buf[16];
#pragma unroll
        for (int k = 0; k < 16; ++k) buf[k] = f2b(W[(size_t)(k0 + k) * HH + n]);
        uint4* dst = (uint4*)(Wt + ((size_t)m * 64 + n) * DD + k0);
        dst[0] = *(uint4*)buf;
        dst[1] = *(uint4*)(buf + 8);
        return;
    }
    const int unit = blockIdx.x * 4 + (threadIdx.x >> 6);
    const int lane = threadIdx.x & 63;
    const int i64 = unit >> 7;    // 64 i-tiles (of 64 rows)
    const int j32 = unit & 127;   // 128 j-tiles (of 32 cols)
    const int i = i64 * 64 + lane;
    const int* p = dag + (size_t)i * TT + j32 * 32;
    u32 rw = 0;
#pragma unroll
    for (int c = 0; c < 32; c += 4) {
        int4 v = *(const int4*)(p + c);
        rw |= (v.x != 0 ? 1u : 0u) << c;
        rw |= (v.y != 0 ? 1u : 0u) << (c + 1);
        rw |= (v.z != 0 ? 1u : 0u) << (c + 2);
        rw |= (v.w != 0 ? 1u : 0u) << (c + 3);
    }
    bits[(size_t)i * TW + j32] = rw;
    u32 myw = 0;
#pragma unroll
    for (int c = 0; c < 32; ++c) {
        unsigned long long m = __ballot((rw >> c) & 1);
        u32 part = (lane < 32) ? (u32)m : (u32)(m >> 32);
        if ((lane & 31) == c) myw = part;
    }
    bitsT[(size_t)(j32 * 32 + (lane & 31)) * TW + i64 * 2 + (lane >> 5)] = myw;
}

// ---------------------------------------------------------------------------
// Fused QKV projection via MFMA: A = X rows (bf16 on the fly), B = Wt.
// Block 256 thr = 4 waves, wave = 32 rows. Grid 128.
// ---------------------------------------------------------------------------
__global__ __launch_bounds__(256) void proj_kernel(const float* __restrict__ X,
                                                   const u16* __restrict__ Wt,
                                                   u16* __restrict__ Qb,
                                                   u16* __restrict__ Kb,
                                                   float* __restrict__ Vf) {
    const int w = threadIdx.x >> 6, lane = threadIdx.x & 63;
    const int l31 = lane & 31, hf = lane >> 5;
    const int row0 = blockIdx.x * 128 + w * 32;
    const float* xr = X + (size_t)(row0 + l31) * DD + hf * 8;

    f32x16 acc[3][2] = {};

    for (int kt = 0; kt < 32; ++kt) {
        float4 x0 = *(const float4*)(xr + kt * 16);
        float4 x1 = *(const float4*)(xr + kt * 16 + 4);
        uint4 aw;
        aw.x = pk2(x0.x, x0.y);
        aw.y = pk2(x0.z, x0.w);
        aw.z = pk2(x1.x, x1.y);
        aw.w = pk2(x1.z, x1.w);
        bf16x8 xa = __builtin_bit_cast(bf16x8, aw);
        const u16* wk = Wt + kt * 16 + hf * 8;
#pragma unroll
        for (int m = 0; m < 3; ++m)
#pragma unroll
            for (int nt = 0; nt < 2; ++nt) {
                bf16x8 wb = ldf(wk + (size_t)(m * 64 + nt * 32 + l31) * DD);
                acc[m][nt] = __builtin_amdgcn_mfma_f32_32x32x16_bf16(xa, wb, acc[m][nt], 0, 0, 0);
            }
    }
#pragma unroll
    for (int nt = 0; nt < 2; ++nt)
#pragma unroll
        for (int r = 0; r < 16; ++r) {
            int rl = (r & 3) + 8 * (r >> 2) + 4 * hf;
            size_t o = (size_t)(row0 + rl) * HH + nt * 32 + l31;
            Qb[o] = f2b(acc[0][nt][r]);
            Kb[o] = f2b(acc[1][nt][r]);
            Vf[o] = acc[2][nt][r];
        }
}

// ---------------------------------------------------------------------------
// Stats: c[b,i] = 1 / sum_j mask(i,j)*exp(S_ij)   (0 if row dead).
// Block = 512 thr (8 waves): 2 i-groups of 32, 4-way j-split each.
// XCD-swizzled blockIdx for L2 locality of K.
// ---------------------------------------------------------------------------
__global__ __launch_bounds__(512) void stats_kernel(const u16* __restrict__ Qb,
                                                    const u16* __restrict__ Kb,
                                                    const u32* __restrict__ bits,
                                                    float* __restrict__ cOut) {
    __shared__ float Lsh[8][64];
    const int logical = (blockIdx.x & 7) * 32 + (blockIdx.x >> 3);
    const int b = logical >> 6, it2 = logical & 63;
    const int i0 = it2 * 64;
    const int w = threadIdx.x >> 6, lane = threadIdx.x & 63;
    const int ig = w >> 2, ws = w & 3;
    const int l31 = lane & 31, hf = lane >> 5;
    const int iw = i0 + ig * 32;

    bf16x8 qf[4];
    const u16* qbase = Qb + ((size_t)b * TT + iw + l31) * HH + hf * 8;
#pragma unroll
    for (int kt = 0; kt < 4; ++kt) qf[kt] = ldf(qbase + kt * 16);

    const u32* brow = bits + (size_t)(iw + l31) * TW;
    float Lp = 0.f;
    for (int jt = ws; jt < 128; jt += 4) {
        const u16* kb = Kb + ((size_t)b * TT + jt * 32 + l31) * HH + hf * 8;
        f32x16 s = {};
        s = __builtin_amdgcn_mfma_f32_32x32x16_bf16(ldf(kb), qf[0], s, 0, 0, 0);
        s = __builtin_amdgcn_mfma_f32_32x32x16_bf16(ldf(kb + 16), qf[1], s, 0, 0, 0);
        s = __builtin_amdgcn_mfma_f32_32x32x16_bf16(ldf(kb + 32), qf[2], s, 0, 0, 0);
        s = __builtin_amdgcn_mfma_f32_32x32x16_bf16(ldf(kb + 48), qf[3], s, 0, 0, 0);
        u32 mw = brow[jt];
        u32 mwr = __builtin_amdgcn_alignbit(mw, mw, hf * 4);  // rotr by 4*hf
#pragma unroll
        for (int r = 0; r < 16; ++r) {
            const int pos = (r & 3) + 8 * (r >> 2);
            float e = __builtin_amdgcn_exp2f(s[r] * SC);
            Lp += ((mwr >> pos) & 1) ? e : 0.f;
        }
    }
    Lsh[w][lane] = Lp;
    __syncthreads();
    if (threadIdx.x < 64) {
        const int g = threadIdx.x >> 5, il = threadIdx.x & 31;
        float L = 0.f;
#pragma unroll
        for (int q = 0; q < 4; ++q) L += Lsh[g * 4 + q][il] + Lsh[g * 4 + q][il + 32];
        cOut[(size_t)b * TT + i0 + g * 32 + il] = (L > 0.f) ? 1.f / L : 0.f;
    }
}

// ---------------------------------------------------------------------------
// Scale V rows by c_i, write transposed bf16 Vt[b][h][i].
// ---------------------------------------------------------------------------
__global__ __launch_bounds__(256) void scalev_kernel(const float* __restrict__ Vf,
                                                     const float* __restrict__ cB,
                                                     u16* __restrict__ Vt) {
    __shared__ u16 Lt[64][72];
    const int blk = blockIdx.x;
    const int b = blk >> 6, it = blk & 63;
    const int i0 = it * 64;
    const int t = threadIdx.x;
    const int row = t >> 2, seg = t & 3;
    const float cv = cB[(size_t)b * TT + i0 + row];
    const float* src = Vf + ((size_t)b * TT + i0 + row) * HH + seg * 16;
#pragma unroll
    for (int k = 0; k < 16; k += 4) {
        float4 v = *(const float4*)(src + k);
        Lt[seg * 16 + k + 0][row] = f2b(v.x * cv);
        Lt[seg * 16 + k + 1][row] = f2b(v.y * cv);
        Lt[seg * 16 + k + 2][row] = f2b(v.z * cv);
        Lt[seg * 16 + k + 3][row] = f2b(v.w * cv);
    }
    __syncthreads();
    const int h = row, cs = seg * 16;
    uint4 q0 = *(const uint4*)&Lt[h][cs];
    uint4 q1 = *(const uint4*)&Lt[h][cs + 8];
    u16* dst = Vt + ((size_t)b * HH + h) * TT + i0 + cs;
    *(uint4*)dst = q0;
    *(uint4*)(dst + 8) = q1;
}

// ---------------------------------------------------------------------------
// Output: out[b,j,h] = swish( sum_i mask*exp(S_ij) * Vt[h][i] ).
// Block = 512 thr (8 waves): 2 j-groups of 32, 4-way i-split each.
// P-transpose to A-frags via cvt_pk + v_permlane32_swap. XCD-swizzled.
// ---------------------------------------------------------------------------
__global__ __launch_bounds__(512) void out_kernel(const u16* __restrict__ Qb,
                                                  const u16* __restrict__ Kb,
                                                  const u16* __restrict__ Vt,
                                                  const u32* __restrict__ bitsT,
                                                  float* __restrict__ out) {
    __shared__ float red[2][4][2048];
    const int logical = (blockIdx.x & 7) * 32 + (blockIdx.x >> 3);
    const int b = logical >> 6, jt2 = logical & 63;
    const int w = threadIdx.x >> 6, lane = threadIdx.x & 63;
    const int g = w >> 2, ws = w & 3;
    const int l31 = lane & 31, hf = lane >> 5;
    const int j0 = jt2 * 64 + g * 32;

    bf16x8 kf[4];
    const u16* kbase = Kb + ((size_t)b * TT + j0 + l31) * HH + hf * 8;
#pragma unroll
    for (int kt = 0; kt < 4; ++kt) kf[kt] = ldf(kbase + kt * 16);

    const u16* qb0 = Qb + (size_t)b * TT * HH + hf * 8;
    const u16* vb0 = Vt + (size_t)b * HH * TT + (size_t)l31 * TT + hf * 8;
    const u32* btc = bitsT + (size_t)(j0 + l31) * TW;

    f32x16 acc0 = {}, acc1 = {};

    for (int it = ws; it < 128; it += 4) {
        const u16* qr = qb0 + (size_t)(it * 32 + l31) * HH;
        f32x16 s = {};
        s = __builtin_amdgcn_mfma_f32_32x32x16_bf16(ldf(qr), kf[0], s, 0, 0, 0);
        s = __builtin_amdgcn_mfma_f32_32x32x16_bf16(ldf(qr + 16), kf[1], s, 0, 0, 0);
        s = __builtin_amdgcn_mfma_f32_32x32x16_bf16(ldf(qr + 32), kf[2], s, 0, 0, 0);
        s = __builtin_amdgcn_mfma_f32_32x32x16_bf16(ldf(qr + 48), kf[3], s, 0, 0, 0);

        u32 mw = btc[it];
        u32 mwr = __builtin_amdgcn_alignbit(mw, mw, hf * 4);  // rotr by 4*hf
        const u16* vb = vb0 + it * 32;

        float p[16];
#pragma unroll
        for (int r = 0; r < 16; ++r) {
            const int pos = (r & 3) + 8 * (r >> 2);
            float e = __builtin_amdgcn_exp2f(s[r] * SC);
            p[r] = ((mwr >> pos) & 1) ? e : 0.f;
        }

#pragma unroll
        for (int k2 = 0; k2 < 2; ++k2) {
            u32 a  = pk2(p[8 * k2 + 0], p[8 * k2 + 1]);
            u32 bq = pk2(p[8 * k2 + 2], p[8 * k2 + 3]);
            u32 c  = pk2(p[8 * k2 + 4], p[8 * k2 + 5]);
            u32 d  = pk2(p[8 * k2 + 6], p[8 * k2 + 7]);
            swap32(a, c);
            swap32(bq, d);
            uint4 aww = {a, bq, c, d};
            bf16x8 pa = __builtin_bit_cast(bf16x8, aww);
            bf16x8 v0 = ldf(vb + k2 * 16);
            bf16x8 v1 = ldf(vb + (size_t)32 * TT + k2 * 16);
            acc0 = __builtin_amdgcn_mfma_f32_32x32x16_bf16(pa, v0, acc0, 0, 0, 0);
            acc1 = __builtin_amdgcn_mfma_f32_32x32x16_bf16(pa, v1, acc1, 0, 0, 0);
        }
    }

    float* myred = &red[g][ws][0];
#pragma unroll
    for (int r = 0; r < 16; ++r) {
        int jl = (r & 3) + 8 * (r >> 2) + 4 * hf;
        myred[jl * 64 + l31] = acc0[r];
        myred[jl * 64 + 32 + l31] = acc1[r];
    }
    __syncthreads();
    {
        const int g2 = threadIdx.x >> 8, t2 = threadIdx.x & 255;
#pragma unroll
        for (int q = 0; q < 8; ++q) {
            int e = t2 + q * 256;
            float v = red[g2][0][e] + red[g2][1][e] + red[g2][2][e] + red[g2][3][e];
            v = v / (1.f + __expf(-v));
            int jl = e >> 6, hc = e & 63;
            out[((size_t)b * TT + jt2 * 64 + g2 * 32 + jl) * HH + hc] = v;
        }
    }
}

// ---------------------------------------------------------------------------
extern "C" void kernel_launch(void* const* d_in, const int* in_sizes, int n_in,
                              void* d_out, int out_size, void* d_ws, size_t ws_size,
                              hipStream_t stream) {
    const float* X  = (const float*)d_in[0];
    const int*  dag = (const int*)d_in[1];
    const float* Wk = (const float*)d_in[2];
    const float* Wq = (const float*)d_in[3];
    const float* Wv = (const float*)d_in[4];
    float* out = (float*)d_out;

    char* ws = (char*)d_ws;
    u16*   Qb    = (u16*)ws;                               // 2 MB
    u16*   Kb    = (u16*)(ws + (2u << 20));                // 2 MB
    float* Vf    = (float*)(ws + (4u << 20));              // 4 MB
    u16*   Vt    = (u16*)(ws + (8u << 20));                // 2 MB (written in scalev)
    u16*   Wt    = (u16*)(ws + (8u << 20));                // 192 KB, overlaps Vt
                                                           // (Wt dead before scalev runs)
    float* cB    = (float*)(ws + (10u << 20));             // 64 KB
    u32*   bits  = (u32*)(ws + (10u << 20) + (1u << 16));  // 2 MB
    u32*   bitsT = (u32*)(ws + (12u << 20) + (1u << 16));  // 2 MB

    pack_kernel<<<2048 + 24, 256, 0, stream>>>(dag, bits, bitsT, Wq, Wk, Wv, Wt);
    proj_kernel<<<128, 256, 0, stream>>>(X, Wt, Qb, Kb, Vf);
    stats_kernel<<<256, 512, 0, stream>>>(Qb, Kb, bits, cB);
    scalev_kernel<<<BB * 64, 256, 0, stream>>>(Vf, cB, Vt);
    out_kernel<<<256, 512, 0, stream>>>(Qb, Kb, Vt, bitsT, out);
}

// Round 4
// 158.552 us; speedup vs baseline: 5.3736x; 1.0279x over previous
//
#include <hip/hip_runtime.h>
#include <hip/hip_bf16.h>
#include <math.h>

#define BB 4
#define TT 4096
#define DD 512
#define HH 64
#define TW 128   // TT/32 bitmask words per row

typedef unsigned int u32;
typedef unsigned short u16;
typedef float f32x16 __attribute__((ext_vector_type(16)));
typedef __bf16 bf16x8 __attribute__((ext_vector_type(8)));

#define SC 0.18033688011112042f  /* 0.125 * log2(e) */

static __device__ __forceinline__ u16 f2b(float f) {
    __hip_bfloat16 h = __float2bfloat16(f);
    return __builtin_bit_cast(u16, h);
}
static __device__ __forceinline__ float b2f(u16 x) {
    return __builtin_bit_cast(float, (u32)x << 16);
}
static __device__ __forceinline__ u32 pk2(float a, float b) {
    return (u32)f2b(a) | ((u32)f2b(b) << 16);
}
static __device__ __forceinline__ bf16x8 ldf(const u16* p) {
    uint4 u = *(const uint4*)p;
    return __builtin_bit_cast(bf16x8, u);
}
// swap high 32 lanes of a with low 32 lanes of b (both results used)
static __device__ __forceinline__ void swap32(u32& a, u32& b) {
    asm("v_permlane32_swap_b32 %0, %1" : "+v"(a), "+v"(b));
}

// ---------------------------------------------------------------------------
// Pack dag into row-major bits[i][j/32] AND col-major bitsT[j][i/32].
// Tail blocks (>=2048): transpose W{q,k,v} fp32 [512][64] -> bf16 Wt[3][64][512].
// ---------------------------------------------------------------------------
__global__ __launch_bounds__(256) void pack_kernel(const int* __restrict__ dag,
                                                   u32* __restrict__ bits,
                                                   u32* __restrict__ bitsT,
                                                   const float* __restrict__ Wq,
                                                   const float* __restrict__ Wk,
                                                   const float* __restrict__ Wv,
                                                   u16* __restrict__ Wt) {
    if (blockIdx.x >= 2048) {
        const int wb = blockIdx.x - 2048;     // 0..23
        const int m = wb >> 3, sub = wb & 7;
        const float* W = (m == 0) ? Wq : (m == 1) ? Wk : Wv;
        const int t = threadIdx.x;
        const int n = sub * 8 + (t >> 5);
        const int k0 = (t & 31) * 16;
        u16 buf[16];
#pragma unroll
        for (int k = 0; k < 16; ++k) buf[k] = f2b(W[(size_t)(k0 + k) * HH + n]);
        uint4* dst = (uint4*)(Wt + ((size_t)m * 64 + n) * DD + k0);
        dst[0] = *(uint4*)buf;
        dst[1] = *(uint4*)(buf + 8);
        return;
    }
    const int unit = blockIdx.x * 4 + (threadIdx.x >> 6);
    const int lane = threadIdx.x & 63;
    const int i64 = unit >> 7;    // 64 i-tiles (of 64 rows)
    const int j32 = unit & 127;   // 128 j-tiles (of 32 cols)
    const int i = i64 * 64 + lane;
    const int* p = dag + (size_t)i * TT + j32 * 32;
    u32 rw = 0;
#pragma unroll
    for (int c = 0; c < 32; c += 4) {
        int4 v = *(const int4*)(p + c);
        rw |= (v.x != 0 ? 1u : 0u) << c;
        rw |= (v.y != 0 ? 1u : 0u) << (c + 1);
        rw |= (v.z != 0 ? 1u : 0u) << (c + 2);
        rw |= (v.w != 0 ? 1u : 0u) << (c + 3);
    }
    bits[(size_t)i * TW + j32] = rw;
    u32 myw = 0;
#pragma unroll
    for (int c = 0; c < 32; ++c) {
        unsigned long long m = __ballot((rw >> c) & 1);
        u32 part = (lane < 32) ? (u32)m : (u32)(m >> 32);
        if ((lane & 31) == c) myw = part;
    }
    bitsT[(size_t)(j32 * 32 + (lane & 31)) * TW + i64 * 2 + (lane >> 5)] = myw;
}

// ---------------------------------------------------------------------------
// Fused QKV projection via MFMA. Block 384 thr = 6 waves:
// wave w -> mat m = w%3 (Q/K/V), row-group rg = w/3. All outputs bf16.
// ---------------------------------------------------------------------------
__global__ __launch_bounds__(384) void proj_kernel(const float* __restrict__ X,
                                                   const u16* __restrict__ Wt,
                                                   u16* __restrict__ Qb,
                                                   u16* __restrict__ Kb,
                                                   u16* __restrict__ Vf) {
    const int w = threadIdx.x >> 6, lane = threadIdx.x & 63;
    const int m = w % 3, rg = w / 3;
    const int l31 = lane & 31, hf = lane >> 5;
    const int row0 = blockIdx.x * 64 + rg * 32;
    const float* xr = X + (size_t)(row0 + l31) * DD + hf * 8;
    const u16* wbase = Wt + (size_t)m * 64 * DD + hf * 8;

    f32x16 acc[2] = {};

    for (int kt = 0; kt < 32; ++kt) {
        float4 x0 = *(const float4*)(xr + kt * 16);
        float4 x1 = *(const float4*)(xr + kt * 16 + 4);
        uint4 aw;
        aw.x = pk2(x0.x, x0.y);
        aw.y = pk2(x0.z, x0.w);
        aw.z = pk2(x1.x, x1.y);
        aw.w = pk2(x1.z, x1.w);
        bf16x8 xa = __builtin_bit_cast(bf16x8, aw);
        const u16* wk = wbase + kt * 16;
#pragma unroll
        for (int nt = 0; nt < 2; ++nt) {
            bf16x8 wb = ldf(wk + (size_t)(nt * 32 + l31) * DD);
            acc[nt] = __builtin_amdgcn_mfma_f32_32x32x16_bf16(xa, wb, acc[nt], 0, 0, 0);
        }
    }
    u16* dst = (m == 0) ? Qb : (m == 1) ? Kb : Vf;
#pragma unroll
    for (int nt = 0; nt < 2; ++nt)
#pragma unroll
        for (int r = 0; r < 16; ++r) {
            int rl = (r & 3) + 8 * (r >> 2) + 4 * hf;
            dst[(size_t)(row0 + rl) * HH + nt * 32 + l31] = f2b(acc[nt][r]);
        }
}

// ---------------------------------------------------------------------------
// Stats: c[b,i] = 1 / sum_j mask(i,j)*exp(S_ij)   (0 if row dead).
// Block = 512 thr (8 waves), one 32-i group, 8-way j-split. Grid 512.
// XCD-swizzled blockIdx for L2 locality of K.
// ---------------------------------------------------------------------------
__global__ __launch_bounds__(512, 4) void stats_kernel(const u16* __restrict__ Qb,
                                                       const u16* __restrict__ Kb,
                                                       const u32* __restrict__ bits,
                                                       float* __restrict__ cOut) {
    __shared__ float Lsh[8][64];
    const int logical = (blockIdx.x & 7) * 64 + (blockIdx.x >> 3);
    const int b = logical >> 7, itg = logical & 127;
    const int i0 = itg * 32;
    const int w = threadIdx.x >> 6, lane = threadIdx.x & 63;
    const int l31 = lane & 31, hf = lane >> 5;

    bf16x8 qf[4];
    const u16* qbase = Qb + ((size_t)b * TT + i0 + l31) * HH + hf * 8;
#pragma unroll
    for (int kt = 0; kt < 4; ++kt) qf[kt] = ldf(qbase + kt * 16);

    const u32* brow = bits + (size_t)(i0 + l31) * TW;
    float Lp = 0.f;
    for (int jt = w; jt < 128; jt += 8) {
        const u16* kb = Kb + ((size_t)b * TT + jt * 32 + l31) * HH + hf * 8;
        f32x16 s = {};
        s = __builtin_amdgcn_mfma_f32_32x32x16_bf16(ldf(kb), qf[0], s, 0, 0, 0);
        s = __builtin_amdgcn_mfma_f32_32x32x16_bf16(ldf(kb + 16), qf[1], s, 0, 0, 0);
        s = __builtin_amdgcn_mfma_f32_32x32x16_bf16(ldf(kb + 32), qf[2], s, 0, 0, 0);
        s = __builtin_amdgcn_mfma_f32_32x32x16_bf16(ldf(kb + 48), qf[3], s, 0, 0, 0);
        u32 mw = brow[jt];
        u32 mwr = __builtin_amdgcn_alignbit(mw, mw, hf * 4);  // rotr by 4*hf
#pragma unroll
        for (int r = 0; r < 16; ++r) {
            const int pos = (r & 3) + 8 * (r >> 2);
            float e = __builtin_amdgcn_exp2f(s[r] * SC);
            Lp += ((mwr >> pos) & 1) ? e : 0.f;
        }
    }
    Lsh[w][lane] = Lp;
    __syncthreads();
    if (threadIdx.x < 32) {
        const int il = threadIdx.x;
        float L = 0.f;
#pragma unroll
        for (int q = 0; q < 8; ++q) L += Lsh[q][il] + Lsh[q][il + 32];
        cOut[(size_t)b * TT + i0 + il] = (L > 0.f) ? 1.f / L : 0.f;
    }
}

// ---------------------------------------------------------------------------
// Scale V rows by c_i, write transposed bf16 Vt[b][h][i].
// ---------------------------------------------------------------------------
__global__ __launch_bounds__(256) void scalev_kernel(const u16* __restrict__ Vf,
                                                     const float* __restrict__ cB,
                                                     u16* __restrict__ Vt) {
    __shared__ u16 Lt[64][72];
    const int blk = blockIdx.x;
    const int b = blk >> 6, it = blk & 63;
    const int i0 = it * 64;
    const int t = threadIdx.x;
    const int row = t >> 2, seg = t & 3;
    const float cv = cB[(size_t)b * TT + i0 + row];
    const u16* src = Vf + ((size_t)b * TT + i0 + row) * HH + seg * 16;
    u16 tmp[16];
    *(uint4*)tmp = *(const uint4*)src;
    *(uint4*)(tmp + 8) = *(const uint4*)(src + 8);
#pragma unroll
    for (int k = 0; k < 16; ++k)
        Lt[seg * 16 + k][row] = f2b(b2f(tmp[k]) * cv);
    __syncthreads();
    const int h = row, cs = seg * 16;
    uint4 q0 = *(const uint4*)&Lt[h][cs];
    uint4 q1 = *(const uint4*)&Lt[h][cs + 8];
    u16* dst = Vt + ((size_t)b * HH + h) * TT + i0 + cs;
    *(uint4*)dst = q0;
    *(uint4*)(dst + 8) = q1;
}

// ---------------------------------------------------------------------------
// Output: out[b,j,h] = swish( sum_i mask*exp(S_ij) * Vt[h][i] ).
// Block = 512 thr (8 waves), one 32-j group, 8-way i-split. Grid 512.
// P-transpose to A-frags via cvt_pk + v_permlane32_swap. XCD-swizzled.
// Staged LDS reduction (32 KB).
// ---------------------------------------------------------------------------
__global__ __launch_bounds__(512, 4) void out_kernel(const u16* __restrict__ Qb,
                                                     const u16* __restrict__ Kb,
                                                     const u16* __restrict__ Vt,
                                                     const u32* __restrict__ bitsT,
                                                     float* __restrict__ out) {
    __shared__ float red[4][2048];
    const int logical = (blockIdx.x & 7) * 64 + (blockIdx.x >> 3);
    const int b = logical >> 7, jt = logical & 127;
    const int j0 = jt * 32;
    const int w = threadIdx.x >> 6, lane = threadIdx.x & 63;
    const int l31 = lane & 31, hf = lane >> 5;

    bf16x8 kf[4];
    const u16* kbase = Kb + ((size_t)b * TT + j0 + l31) * HH + hf * 8;
#pragma unroll
    for (int kt = 0; kt < 4; ++kt) kf[kt] = ldf(kbase + kt * 16);

    const u16* qb0 = Qb + (size_t)b * TT * HH + hf * 8;
    const u16* vb0 = Vt + (size_t)b * HH * TT + (size_t)l31 * TT + hf * 8;
    const u32* btc = bitsT + (size_t)(j0 + l31) * TW;

    f32x16 acc0 = {}, acc1 = {};

    for (int it = w; it < 128; it += 8) {
        const u16* qr = qb0 + (size_t)(it * 32 + l31) * HH;
        f32x16 s = {};
        s = __builtin_amdgcn_mfma_f32_32x32x16_bf16(ldf(qr), kf[0], s, 0, 0, 0);
        s = __builtin_amdgcn_mfma_f32_32x32x16_bf16(ldf(qr + 16), kf[1], s, 0, 0, 0);
        s = __builtin_amdgcn_mfma_f32_32x32x16_bf16(ldf(qr + 32), kf[2], s, 0, 0, 0);
        s = __builtin_amdgcn_mfma_f32_32x32x16_bf16(ldf(qr + 48), kf[3], s, 0, 0, 0);

        u32 mw = btc[it];
        u32 mwr = __builtin_amdgcn_alignbit(mw, mw, hf * 4);  // rotr by 4*hf
        const u16* vb = vb0 + it * 32;

        float p[16];
#pragma unroll
        for (int r = 0; r < 16; ++r) {
            const int pos = (r & 3) + 8 * (r >> 2);
            float e = __builtin_amdgcn_exp2f(s[r] * SC);
            p[r] = ((mwr >> pos) & 1) ? e : 0.f;
        }

#pragma unroll
        for (int k2 = 0; k2 < 2; ++k2) {
            u32 a  = pk2(p[8 * k2 + 0], p[8 * k2 + 1]);
            u32 bq = pk2(p[8 * k2 + 2], p[8 * k2 + 3]);
            u32 c  = pk2(p[8 * k2 + 4], p[8 * k2 + 5]);
            u32 d  = pk2(p[8 * k2 + 6], p[8 * k2 + 7]);
            swap32(a, c);
            swap32(bq, d);
            uint4 aww = {a, bq, c, d};
            bf16x8 pa = __builtin_bit_cast(bf16x8, aww);
            bf16x8 v0 = ldf(vb + k2 * 16);
            bf16x8 v1 = ldf(vb + (size_t)32 * TT + k2 * 16);
            acc0 = __builtin_amdgcn_mfma_f32_32x32x16_bf16(pa, v0, acc0, 0, 0, 0);
            acc1 = __builtin_amdgcn_mfma_f32_32x32x16_bf16(pa, v1, acc1, 0, 0, 0);
        }
    }

    // staged reduction: 8 waves -> 4 -> final sum by all threads
    if (w >= 4) {
        float* myred = &red[w - 4][0];
#pragma unroll
        for (int r = 0; r < 16; ++r) {
            int jl = (r & 3) + 8 * (r >> 2) + 4 * hf;
            myred[jl * 64 + l31] = acc0[r];
            myred[jl * 64 + 32 + l31] = acc1[r];
        }
    }
    __syncthreads();
    if (w < 4) {
        float* myred = &red[w][0];
#pragma unroll
        for (int r = 0; r < 16; ++r) {
            int jl = (r & 3) + 8 * (r >> 2) + 4 * hf;
            acc0[r] += myred[jl * 64 + l31];
            acc1[r] += myred[jl * 64 + 32 + l31];
        }
#pragma unroll
        for (int r = 0; r < 16; ++r) {
            int jl = (r & 3) + 8 * (r >> 2) + 4 * hf;
            myred[jl * 64 + l31] = acc0[r];
            myred[jl * 64 + 32 + l31] = acc1[r];
        }
    }
    __syncthreads();
    {
        const int tid = threadIdx.x;
        float4 r0 = *(const float4*)&red[0][tid * 4];
        float4 r1 = *(const float4*)&red[1][tid * 4];
        float4 r2 = *(const float4*)&red[2][tid * 4];
        float4 r3 = *(const float4*)&red[3][tid * 4];
        float v0 = r0.x + r1.x + r2.x + r3.x;
        float v1 = r0.y + r1.y + r2.y + r3.y;
        float v2 = r0.z + r1.z + r2.z + r3.z;
        float v3 = r0.w + r1.w + r2.w + r3.w;
        v0 = v0 / (1.f + __expf(-v0));
        v1 = v1 / (1.f + __expf(-v1));
        v2 = v2 / (1.f + __expf(-v2));
        v3 = v3 / (1.f + __expf(-v3));
        const int jl = tid >> 4, hc = (tid * 4) & 63;
        float* dst = out + ((size_t)b * TT + j0 + jl) * HH + hc;
        *(float4*)dst = make_float4(v0, v1, v2, v3);
    }
}

// ---------------------------------------------------------------------------
extern "C" void kernel_launch(void* const* d_in, const int* in_sizes, int n_in,
                              void* d_out, int out_size, void* d_ws, size_t ws_size,
                              hipStream_t stream) {
    const float* X  = (const float*)d_in[0];
    const int*  dag = (const int*)d_in[1];
    const float* Wk = (const float*)d_in[2];
    const float* Wq = (const float*)d_in[3];
    const float* Wv = (const float*)d_in[4];
    float* out = (float*)d_out;

    char* ws = (char*)d_ws;
    u16*   Qb    = (u16*)ws;                               // 0..2 MB
    u16*   Kb    = (u16*)(ws + (2u << 20));                // 2..4 MB
    u16*   Vf    = (u16*)(ws + (4u << 20));                // 4..6 MB (bf16, unscaled)
    u16*   Vt    = (u16*)(ws + (6u << 20));                // 6..8 MB (bf16, scaled, transposed)
    u16*   Wt    = (u16*)(ws + (8u << 20));                // 8..8.19 MB
    float* cB    = (float*)(ws + (8u << 20) + (256u << 10)); // 64 KB
    u32*   bits  = (u32*)(ws + (8u << 20) + (512u << 10));  // 2 MB
    u32*   bitsT = (u32*)(ws + (10u << 20) + (512u << 10)); // 2 MB  (total 12.5 MB)

    pack_kernel<<<2048 + 24, 256, 0, stream>>>(dag, bits, bitsT, Wq, Wk, Wv, Wt);
    proj_kernel<<<256, 384, 0, stream>>>(X, Wt, Qb, Kb, Vf);
    stats_kernel<<<512, 512, 0, stream>>>(Qb, Kb, bits, cB);
    scalev_kernel<<<BB * 64, 256, 0, stream>>>(Vf, cB, Vt);
    out_kernel<<<512, 512, 0, stream>>>(Qb, Kb, Vt, bitsT, out);
}

// Round 5
// 97.515 us; speedup vs baseline: 8.7370x; 1.6259x over previous
//
#include <hip/hip_runtime.h>
#include <hip/hip_bf16.h>
#include <math.h>

#define BB 4
#define TT 4096
#define DD 512
#define HH 64
#define TW 128   // TT/32 words

typedef unsigned int u32;
typedef unsigned short u16;
typedef float f32x16 __attribute__((ext_vector_type(16)));
typedef __bf16 bf16x8 __attribute__((ext_vector_type(8)));

#define SC 0.18033688011112042f  /* 0.125 * log2(e) */

static __device__ __forceinline__ u16 f2b(float f) {
    __hip_bfloat16 h = __float2bfloat16(f);
    return __builtin_bit_cast(u16, h);
}
static __device__ __forceinline__ float b2f(u16 x) {
    return __builtin_bit_cast(float, (u32)x << 16);
}
static __device__ __forceinline__ u32 pk2(float a, float b) {
    return (u32)f2b(a) | ((u32)f2b(b) << 16);
}
static __device__ __forceinline__ bf16x8 ldf(const u16* p) {
    uint4 u = *(const uint4*)p;
    return __builtin_bit_cast(bf16x8, u);
}
// swap high 32 lanes of a with low 32 lanes of b (both results used)
static __device__ __forceinline__ void swap32(u32& a, u32& b) {
    asm("v_permlane32_swap_b32 %0, %1" : "+v"(a), "+v"(b));
}

// Fragment-order layouts (the canonical MFMA fragment: lane&31 = row-of-32,
// lane>>5 = k-half, 8 consecutive k per lane):
//   QF/KF: [b*128 + tile][kt=0..3][lane][8 u16]   (row = t, k = d)
//   VF:    [b*128 + tile][hg*2+k2][lane][8 u16]   (row = h = hg*32+lane&31,
//                                                  k = i = k2*16+(lane>>5)*8+e)
//   bits2:  [jt][i]  word = 32 j-bits for row i
//   bitsTT: [it][j]  word = 32 i-bits for col j

// ---------------------------------------------------------------------------
// Pack dag -> bits2 + bitsTT. Tail blocks: W transpose to bf16 Wt[3][64][512].
// ---------------------------------------------------------------------------
__global__ __launch_bounds__(256) void pack_kernel(const int* __restrict__ dag,
                                                   u32* __restrict__ bits2,
                                                   u32* __restrict__ bitsTT,
                                                   const float* __restrict__ Wq,
                                                   const float* __restrict__ Wk,
                                                   const float* __restrict__ Wv,
                                                   u16* __restrict__ Wt) {
    if (blockIdx.x >= 2048) {
        const int wb = blockIdx.x - 2048;     // 0..23
        const int m = wb >> 3, sub = wb & 7;
        const float* W = (m == 0) ? Wq : (m == 1) ? Wk : Wv;
        const int t = threadIdx.x;
        const int n = sub * 8 + (t >> 5);
        const int k0 = (t & 31) * 16;
        u16 buf[16];
#pragma unroll
        for (int k = 0; k < 16; ++k) buf[k] = f2b(W[(size_t)(k0 + k) * HH + n]);
        uint4* dst = (uint4*)(Wt + ((size_t)m * 64 + n) * DD + k0);
        dst[0] = *(uint4*)buf;
        dst[1] = *(uint4*)(buf + 8);
        return;
    }
    const int unit = blockIdx.x * 4 + (threadIdx.x >> 6);
    const int lane = threadIdx.x & 63;
    const int i64 = unit >> 7;    // 64 i-tiles (of 64 rows)
    const int j32 = unit & 127;   // 128 j-tiles (of 32 cols)
    const int i = i64 * 64 + lane;
    const int* p = dag + (size_t)i * TT + j32 * 32;
    u32 rw = 0;
#pragma unroll
    for (int c = 0; c < 32; c += 4) {
        int4 v = *(const int4*)(p + c);
        rw |= (v.x != 0 ? 1u : 0u) << c;
        rw |= (v.y != 0 ? 1u : 0u) << (c + 1);
        rw |= (v.z != 0 ? 1u : 0u) << (c + 2);
        rw |= (v.w != 0 ? 1u : 0u) << (c + 3);
    }
    bits2[(size_t)j32 * TT + i] = rw;
    u32 myw = 0;
#pragma unroll
    for (int c = 0; c < 32; ++c) {
        unsigned long long m = __ballot((rw >> c) & 1);
        u32 part = (lane < 32) ? (u32)m : (u32)(m >> 32);
        if ((lane & 31) == c) myw = part;
    }
    bitsTT[(size_t)(i64 * 2 + (lane >> 5)) * TT + j32 * 32 + (lane & 31)] = myw;
}

// ---------------------------------------------------------------------------
// Fused QKV projection via MFMA. Block 384 thr = 6 waves:
// wave w -> mat m = w%3 (Q/K/V), row-group rg = w/3 (32 rows = 1 tile).
// Q,K stored in fragment order; V row-major bf16 (re-formatted by scalev).
// ---------------------------------------------------------------------------
__global__ __launch_bounds__(384) void proj_kernel(const float* __restrict__ X,
                                                   const u16* __restrict__ Wt,
                                                   u16* __restrict__ QF,
                                                   u16* __restrict__ KF,
                                                   u16* __restrict__ Vf) {
    const int w = threadIdx.x >> 6, lane = threadIdx.x & 63;
    const int m = w % 3, rg = w / 3;
    const int l31 = lane & 31, hf = lane >> 5;
    const int tile = blockIdx.x * 2 + rg;       // global 32-row tile id
    const int row0 = tile * 32;
    const float* xr = X + (size_t)(row0 + l31) * DD + hf * 8;
    const u16* wbase = Wt + (size_t)m * 64 * DD + hf * 8;

    f32x16 acc[2] = {};

    for (int kt = 0; kt < 32; ++kt) {
        float4 x0 = *(const float4*)(xr + kt * 16);
        float4 x1 = *(const float4*)(xr + kt * 16 + 4);
        uint4 aw;
        aw.x = pk2(x0.x, x0.y);
        aw.y = pk2(x0.z, x0.w);
        aw.z = pk2(x1.x, x1.y);
        aw.w = pk2(x1.z, x1.w);
        bf16x8 xa = __builtin_bit_cast(bf16x8, aw);
        const u16* wk = wbase + kt * 16;
#pragma unroll
        for (int nt = 0; nt < 2; ++nt) {
            bf16x8 wb = ldf(wk + (size_t)(nt * 32 + l31) * DD);
            acc[nt] = __builtin_amdgcn_mfma_f32_32x32x16_bf16(xa, wb, acc[nt], 0, 0, 0);
        }
    }
    if (m < 2) {
        u16* dst = (m == 0) ? QF : KF;
        const int kth = l31 >> 4, hfp = (l31 >> 3) & 1, e = l31 & 7;
#pragma unroll
        for (int nt = 0; nt < 2; ++nt)
#pragma unroll
            for (int r = 0; r < 16; ++r) {
                int rl = (r & 3) + 8 * (r >> 2) + 4 * hf;
                dst[(size_t)tile * 2048 + (nt * 2 + kth) * 512 + (rl + hfp * 32) * 8 + e]
                    = f2b(acc[nt][r]);
            }
    } else {
#pragma unroll
        for (int nt = 0; nt < 2; ++nt)
#pragma unroll
            for (int r = 0; r < 16; ++r) {
                int rl = (r & 3) + 8 * (r >> 2) + 4 * hf;
                Vf[(size_t)(row0 + rl) * HH + nt * 32 + l31] = f2b(acc[nt][r]);
            }
    }
}

// ---------------------------------------------------------------------------
// Stats: c[b,i] = 1 / sum_j mask(i,j)*exp(S_ij)   (0 if row dead).
// Block = 512 thr (8 waves), one 32-i tile, 8-way j-split. Grid 512.
// All operand loads coalesced from fragment-order buffers.
// ---------------------------------------------------------------------------
__global__ __launch_bounds__(512, 4) void stats_kernel(const u16* __restrict__ QF,
                                                       const u16* __restrict__ KF,
                                                       const u32* __restrict__ bits2,
                                                       float* __restrict__ cOut) {
    __shared__ float Lsh[8][64];
    const int logical = (blockIdx.x & 7) * 64 + (blockIdx.x >> 3);
    const int b = logical >> 7, itg = logical & 127;
    const int i0 = itg * 32;
    const int w = threadIdx.x >> 6, lane = threadIdx.x & 63;
    const int l31 = lane & 31, hf = lane >> 5;

    bf16x8 qf[4];
    const u16* qbase = QF + (size_t)(b * 128 + itg) * 2048 + lane * 8;
#pragma unroll
    for (int kt = 0; kt < 4; ++kt) qf[kt] = ldf(qbase + kt * 512);

    float Lp = 0.f;
    for (int jt = w; jt < 128; jt += 8) {
        const u16* kb = KF + (size_t)(b * 128 + jt) * 2048 + lane * 8;
        f32x16 s = {};
        s = __builtin_amdgcn_mfma_f32_32x32x16_bf16(ldf(kb), qf[0], s, 0, 0, 0);
        s = __builtin_amdgcn_mfma_f32_32x32x16_bf16(ldf(kb + 512), qf[1], s, 0, 0, 0);
        s = __builtin_amdgcn_mfma_f32_32x32x16_bf16(ldf(kb + 1024), qf[2], s, 0, 0, 0);
        s = __builtin_amdgcn_mfma_f32_32x32x16_bf16(ldf(kb + 1536), qf[3], s, 0, 0, 0);
        u32 mw = bits2[(size_t)jt * TT + i0 + l31];
        u32 mwr = __builtin_amdgcn_alignbit(mw, mw, hf * 4);  // rotr by 4*hf
#pragma unroll
        for (int r = 0; r < 16; ++r) {
            const int pos = (r & 3) + 8 * (r >> 2);
            float e = __builtin_amdgcn_exp2f(s[r] * SC);
            Lp += ((mwr >> pos) & 1) ? e : 0.f;
        }
    }
    Lsh[w][lane] = Lp;
    __syncthreads();
    if (threadIdx.x < 32) {
        const int il = threadIdx.x;
        float L = 0.f;
#pragma unroll
        for (int q = 0; q < 8; ++q) L += Lsh[q][il] + Lsh[q][il + 32];
        cOut[(size_t)b * TT + i0 + il] = (L > 0.f) ? 1.f / L : 0.f;
    }
}

// ---------------------------------------------------------------------------
// Scale V rows by c_i, emit fragment-order VF tiles.
// Block = 256 thr, covers 64 i-rows (2 tiles).
// ---------------------------------------------------------------------------
__global__ __launch_bounds__(256) void scalev_kernel(const u16* __restrict__ Vf,
                                                     const float* __restrict__ cB,
                                                     u16* __restrict__ VF) {
    __shared__ u16 Lt[64][80];   // [h][i-local], 160B rows (16B-aligned reads)
    const int blk = blockIdx.x;
    const int b = blk >> 6, it2 = blk & 63;
    const int i0 = it2 * 64;
    const int t = threadIdx.x;
    {
        const int row = t >> 2, seg = t & 3;
        const float cv = cB[(size_t)b * TT + i0 + row];
        const u16* src = Vf + ((size_t)b * TT + i0 + row) * HH + seg * 16;
        u16 tmp[16];
        *(uint4*)tmp = *(const uint4*)src;
        *(uint4*)(tmp + 8) = *(const uint4*)(src + 8);
#pragma unroll
        for (int k = 0; k < 16; ++k)
            Lt[seg * 16 + k][row] = f2b(b2f(tmp[k]) * cv);
    }
    __syncthreads();
    {
        const int lane = t & 63, cid = t >> 6;          // cid: (it_local, k2)
        const int itl = cid >> 1, k2 = cid & 1;
        const int l31 = lane & 31, hf = lane >> 5;
        const int icol = itl * 32 + k2 * 16 + hf * 8;
#pragma unroll
        for (int hg = 0; hg < 2; ++hg) {
            uint4 v = *(const uint4*)&Lt[hg * 32 + l31][icol];
            u16* dst = VF + (size_t)(b * 128 + it2 * 2 + itl) * 2048
                          + (hg * 2 + k2) * 512 + lane * 8;
            *(uint4*)dst = v;
        }
    }
}

// ---------------------------------------------------------------------------
// Output: out[b,j,h] = swish( sum_i mask*exp(S_ij) * Vs[i,h] ).
// Block = 512 thr (8 waves), one 32-j tile, 8-way i-split. Grid 512.
// All operand loads coalesced from fragment-order buffers. LDS = reduction only.
// ---------------------------------------------------------------------------
__global__ __launch_bounds__(512, 4) void out_kernel(const u16* __restrict__ QF,
                                                     const u16* __restrict__ KF,
                                                     const u16* __restrict__ VF,
                                                     const u32* __restrict__ bitsTT,
                                                     float* __restrict__ out) {
    __shared__ float red[4][2048];
    const int logical = (blockIdx.x & 7) * 64 + (blockIdx.x >> 3);
    const int b = logical >> 7, jt = logical & 127;
    const int j0 = jt * 32;
    const int w = threadIdx.x >> 6, lane = threadIdx.x & 63;
    const int l31 = lane & 31, hf = lane >> 5;

    bf16x8 kf[4];
    const u16* kbase = KF + (size_t)(b * 128 + jt) * 2048 + lane * 8;
#pragma unroll
    for (int kt = 0; kt < 4; ++kt) kf[kt] = ldf(kbase + kt * 512);

    f32x16 acc0 = {}, acc1 = {};

    for (int it = w; it < 128; it += 8) {
        const u16* qb = QF + (size_t)(b * 128 + it) * 2048 + lane * 8;
        const u16* vb = VF + (size_t)(b * 128 + it) * 2048 + lane * 8;
        u32 mw = bitsTT[(size_t)it * TT + j0 + l31];

        f32x16 s = {};
        s = __builtin_amdgcn_mfma_f32_32x32x16_bf16(ldf(qb), kf[0], s, 0, 0, 0);
        s = __builtin_amdgcn_mfma_f32_32x32x16_bf16(ldf(qb + 512), kf[1], s, 0, 0, 0);
        s = __builtin_amdgcn_mfma_f32_32x32x16_bf16(ldf(qb + 1024), kf[2], s, 0, 0, 0);
        s = __builtin_amdgcn_mfma_f32_32x32x16_bf16(ldf(qb + 1536), kf[3], s, 0, 0, 0);

        u32 mwr = __builtin_amdgcn_alignbit(mw, mw, hf * 4);  // rotr by 4*hf

        float p[16];
#pragma unroll
        for (int r = 0; r < 16; ++r) {
            const int pos = (r & 3) + 8 * (r >> 2);
            float e = __builtin_amdgcn_exp2f(s[r] * SC);
            p[r] = ((mwr >> pos) & 1) ? e : 0.f;
        }

#pragma unroll
        for (int k2 = 0; k2 < 2; ++k2) {
            u32 a  = pk2(p[8 * k2 + 0], p[8 * k2 + 1]);
            u32 bq = pk2(p[8 * k2 + 2], p[8 * k2 + 3]);
            u32 c  = pk2(p[8 * k2 + 4], p[8 * k2 + 5]);
            u32 d  = pk2(p[8 * k2 + 6], p[8 * k2 + 7]);
            swap32(a, c);
            swap32(bq, d);
            uint4 aww = {a, bq, c, d};
            bf16x8 pa = __builtin_bit_cast(bf16x8, aww);
            bf16x8 v0 = ldf(vb + k2 * 512);          // hg=0
            bf16x8 v1 = ldf(vb + (2 + k2) * 512);    // hg=1
            acc0 = __builtin_amdgcn_mfma_f32_32x32x16_bf16(pa, v0, acc0, 0, 0, 0);
            acc1 = __builtin_amdgcn_mfma_f32_32x32x16_bf16(pa, v1, acc1, 0, 0, 0);
        }
    }

    // staged reduction: 8 waves -> 4 -> final sum by all threads
    if (w >= 4) {
        float* myred = &red[w - 4][0];
#pragma unroll
        for (int r = 0; r < 16; ++r) {
            int jl = (r & 3) + 8 * (r >> 2) + 4 * hf;
            myred[jl * 64 + l31] = acc0[r];
            myred[jl * 64 + 32 + l31] = acc1[r];
        }
    }
    __syncthreads();
    if (w < 4) {
        float* myred = &red[w][0];
#pragma unroll
        for (int r = 0; r < 16; ++r) {
            int jl = (r & 3) + 8 * (r >> 2) + 4 * hf;
            acc0[r] += myred[jl * 64 + l31];
            acc1[r] += myred[jl * 64 + 32 + l31];
        }
#pragma unroll
        for (int r = 0; r < 16; ++r) {
            int jl = (r & 3) + 8 * (r >> 2) + 4 * hf;
            myred[jl * 64 + l31] = acc0[r];
            myred[jl * 64 + 32 + l31] = acc1[r];
        }
    }
    __syncthreads();
    {
        const int tid = threadIdx.x;
        float4 r0 = *(const float4*)&red[0][tid * 4];
        float4 r1 = *(const float4*)&red[1][tid * 4];
        float4 r2 = *(const float4*)&red[2][tid * 4];
        float4 r3 = *(const float4*)&red[3][tid * 4];
        float v0 = r0.x + r1.x + r2.x + r3.x;
        float v1 = r0.y + r1.y + r2.y + r3.y;
        float v2 = r0.z + r1.z + r2.z + r3.z;
        float v3 = r0.w + r1.w + r2.w + r3.w;
        v0 = v0 / (1.f + __expf(-v0));
        v1 = v1 / (1.f + __expf(-v1));
        v2 = v2 / (1.f + __expf(-v2));
        v3 = v3 / (1.f + __expf(-v3));
        const int jl = tid >> 4, hc = (tid * 4) & 63;
        float* dst = out + ((size_t)b * TT + j0 + jl) * HH + hc;
        *(float4*)dst = make_float4(v0, v1, v2, v3);
    }
}

// ---------------------------------------------------------------------------
extern "C" void kernel_launch(void* const* d_in, const int* in_sizes, int n_in,
                              void* d_out, int out_size, void* d_ws, size_t ws_size,
                              hipStream_t stream) {
    const float* X  = (const float*)d_in[0];
    const int*  dag = (const int*)d_in[1];
    const float* Wk = (const float*)d_in[2];
    const float* Wq = (const float*)d_in[3];
    const float* Wv = (const float*)d_in[4];
    float* out = (float*)d_out;

    char* ws = (char*)d_ws;
    u16*   QF    = (u16*)ws;                                // 0..2 MB (fragment order)
    u16*   KF    = (u16*)(ws + (2u << 20));                 // 2..4 MB
    u16*   Vf    = (u16*)(ws + (4u << 20));                 // 4..6 MB row-major bf16
    u16*   VF    = (u16*)(ws + (6u << 20));                 // 6..8 MB fragment order
    u32*   bits2 = (u32*)(ws + (8u << 20));                 // 8..10 MB  [jt][i]
    u32*   bitsTT= (u32*)(ws + (10u << 20));                // 10..12 MB [it][j]
    u16*   Wt    = (u16*)(ws + (12u << 20));                // 192 KB
    float* cB    = (float*)(ws + (12u << 20) + (256u << 10)); // 64 KB

    pack_kernel<<<2048 + 24, 256, 0, stream>>>(dag, bits2, bitsTT, Wq, Wk, Wv, Wt);
    proj_kernel<<<256, 384, 0, stream>>>(X, Wt, QF, KF, Vf);
    stats_kernel<<<512, 512, 0, stream>>>(QF, KF, bits2, cB);
    scalev_kernel<<<BB * 64, 256, 0, stream>>>(Vf, cB, VF);
    out_kernel<<<512, 512, 0, stream>>>(QF, KF, VF, bitsTT, out);
}